// Round 1
// baseline (579.677 us; speedup 1.0000x reference)
//
#include <hip/hip_runtime.h>
#include <hip/hip_bf16.h>

// GCNConv encoder — R15:
//   passA:  ACH=2048, single global edge read, LDS multisplit -> buckets (CAP=4096)  [unchanged]
//   B1deg:  histogram degree -> dinv, scale h*=dinv in place (no longer writes out)
//   B2:     NO sort. Direct ds_add_f32 accumulation into oacc[128][32] LDS tile,
//           MLP-16 gather batches; single fused (neigh+self)*dinv+bias float4 store.
//   gemm:   64-row tile (33.4 KB LDS)  [unchanged]
//
// ws: dinv[n] f32 | h[n*32] bf16 | bucketed[NB*CAP] u32 | bcursor[1024] ~= 19.7 MB

#define LATD 32
#define INCH 128
#define BSH 7
#define BW 128
#define CAP 4096
#define ACH 2048

__device__ __forceinline__ void load_edge(const int* __restrict__ ei, const int* __restrict__ yei,
                                          int e1, int e2, int e, int& src, int& dst) {
    if (e < e1) { src = ei[e]; dst = ei[e1 + e]; }
    else        { int t = e - e1; src = yei[t]; dst = yei[e2 + t]; }
}

// ---------------- GEMM v3 (proven R14): 64-row tile, bf16 x-staging, 256 thr ----------------
__global__ __launch_bounds__(256) void gemm_tile_k(const float* __restrict__ x,
                                                   const float* __restrict__ W,
                                                   __hip_bfloat16* __restrict__ h, int n) {
    __shared__ __hip_bfloat16 xs[64][136];
    __shared__ float Wl[INCH][LATD];
    int tid = threadIdx.x;
    {
        const float4* Wv = (const float4*)W;
        float4* Wlv = (float4*)&Wl[0][0];
#pragma unroll 2
        for (int i = 0; i < 4; ++i) Wlv[tid + 256 * i] = Wv[tid + 256 * i];
    }
    int row0 = blockIdx.x * 64;
#pragma unroll 4
    for (int v = tid; v < 64 * 32; v += 256) {
        int r = v >> 5, kc = v & 31;
        int gr = row0 + r;
        float4 val = make_float4(0.f, 0.f, 0.f, 0.f);
        if (gr < n) val = ((const float4*)(x + (size_t)gr * INCH))[kc];
        __hip_bfloat16 t4[4] = { __float2bfloat16(val.x), __float2bfloat16(val.y),
                                 __float2bfloat16(val.z), __float2bfloat16(val.w) };
        *(ushort4*)&xs[r][kc * 4] = *(const ushort4*)t4;
    }
    __syncthreads();
    int c = tid & 7, rr = tid >> 3;
    int j0 = c * 4, r0 = rr * 2;
    float acc[2][4] = {};
#pragma unroll 2
    for (int kk = 0; kk < INCH; kk += 4) {
        float4 w0 = *(const float4*)&Wl[kk + 0][j0];
        float4 w1 = *(const float4*)&Wl[kk + 1][j0];
        float4 w2 = *(const float4*)&Wl[kk + 2][j0];
        float4 w3 = *(const float4*)&Wl[kk + 3][j0];
#pragma unroll
        for (int ri = 0; ri < 2; ++ri) {
            ushort4 u = *(const ushort4*)&xs[r0 + ri][kk];
            float a0 = __bfloat162float(*(const __hip_bfloat16*)&u.x);
            float a1 = __bfloat162float(*(const __hip_bfloat16*)&u.y);
            float a2 = __bfloat162float(*(const __hip_bfloat16*)&u.z);
            float a3 = __bfloat162float(*(const __hip_bfloat16*)&u.w);
            acc[ri][0] += a0 * w0.x + a1 * w1.x + a2 * w2.x + a3 * w3.x;
            acc[ri][1] += a0 * w0.y + a1 * w1.y + a2 * w2.y + a3 * w3.y;
            acc[ri][2] += a0 * w0.z + a1 * w1.z + a2 * w2.z + a3 * w3.z;
            acc[ri][3] += a0 * w0.w + a1 * w1.w + a2 * w2.w + a3 * w3.w;
        }
    }
#pragma unroll
    for (int ri = 0; ri < 2; ++ri) {
        int gr = row0 + r0 + ri;
        if (gr < n) {
            __hip_bfloat16 tmp[4];
#pragma unroll
            for (int cj = 0; cj < 4; ++cj) tmp[cj] = __float2bfloat16(acc[ri][cj]);
            *(ushort4*)(&h[(size_t)gr * LATD + j0]) = *(const ushort4*)tmp;
        }
    }
}

__global__ void zero_i32_k(int* p, int cnt) {
    int i = blockIdx.x * 256 + threadIdx.x;
    if (i < cnt) p[i] = 0;
}

// ---------------- pass A: single-global-read multisplit (ACH=2048) ----------------
__global__ __launch_bounds__(512) void passA_scatter_k(const int* __restrict__ ei, const int* __restrict__ yei,
                                                       int e1, int e2, int* __restrict__ bcursor,
                                                       unsigned* __restrict__ bucketed, int NB) {
    __shared__ int hist[1024];
    __shared__ int scanex[1024];
    __shared__ int segb[1024];
    __shared__ int sd[512];
    __shared__ unsigned raw[ACH];           // pk in arrival order
    __shared__ unsigned short rawb[ACH];    // bucket in arrival order
    __shared__ unsigned stage[ACH];         // pk sorted by bucket
    __shared__ unsigned short bof[ACH];     // bucket sorted
    int tid = threadIdx.x;
    int E = e1 + e2;
    int e0 = blockIdx.x * ACH;
    int m = E - e0; if (m > ACH) m = ACH;
    for (int i = tid; i < 1024; i += 512) hist[i] = 0;
    __syncthreads();
    for (int i = tid; i < m; i += 512) {
        int src, dst; load_edge(ei, yei, e1, e2, e0 + i, src, dst);
        int b = dst >> BSH;
        raw[i]  = ((unsigned)src << BSH) | (unsigned)(dst & (BW - 1));
        rawb[i] = (unsigned short)b;
        atomicAdd(&hist[b], 1);
    }
    __syncthreads();
    int b2 = tid * 2;
    int c0 = hist[b2], c1 = hist[b2 + 1];
    int tot2 = c0 + c1;
    sd[tid] = tot2;
    __syncthreads();
    int val = tot2;
    for (int off = 1; off < 512; off <<= 1) {
        int t = (tid >= off) ? sd[tid - off] : 0;
        __syncthreads();
        val += t;
        sd[tid] = val;
        __syncthreads();
    }
    int eb = val - tot2;
    scanex[b2] = eb; scanex[b2 + 1] = eb + c0;
    __syncthreads();
    for (int b = tid; b < NB; b += 512)
        segb[b] = hist[b] ? atomicAdd(&bcursor[b], hist[b]) : 0;
    __syncthreads();
    for (int b = tid; b < 1024; b += 512) hist[b] = scanex[b];   // repurpose as cursor
    __syncthreads();
    for (int i = tid; i < m; i += 512) {
        unsigned pk = raw[i]; int b = rawb[i];
        int pos = atomicAdd(&hist[b], 1);
        stage[pos] = pk;
        bof[pos] = (unsigned short)b;
    }
    __syncthreads();
    for (int i = tid; i < m; i += 512) {
        int b = bof[i];
        int pos = segb[b] + (i - scanex[b]);
        if (pos < CAP)
            bucketed[(size_t)b * CAP + pos] = stage[i];
    }
}

// ---------------- B1deg: histogram degree; dinv; scale h in place ----------------
__global__ __launch_bounds__(512) void passB1deg_k(const unsigned* __restrict__ bucketed,
                                                   const int* __restrict__ bcursor,
                                                   float* __restrict__ dinv, unsigned* __restrict__ h2,
                                                   int n) {
    __shared__ int cnt[BW];
    __shared__ float sdv[BW];
    int tid = threadIdx.x;
    int b = blockIdx.x;
    size_t s = (size_t)b * CAP;
    int tot = bcursor[b]; if (tot > CAP) tot = CAP;
    int dst0 = b << BSH;
    if (tid < BW) cnt[tid] = 0;
    __syncthreads();
    for (int i = tid; i < tot; i += 512)
        atomicAdd(&cnt[bucketed[s + i] & (BW - 1)], 1);
    __syncthreads();
    if (tid < BW) {
        float dv = rsqrtf((float)cnt[tid] + 1.0f);
        sdv[tid] = dv;
        int node = dst0 + tid;
        if (node < n) dinv[node] = dv;
    }
    __syncthreads();
    for (int idx = tid; idx < BW * 16; idx += 512) {
        int ldn = idx >> 4, q = idx & 15;
        int node = dst0 + ldn;
        if (node >= n) continue;
        float dv = sdv[ldn];
        unsigned u = h2[(size_t)node * 16 + q];
        __hip_bfloat162 v = *(__hip_bfloat162*)&u;
        float2 f = __bfloat1622float2(v);
        f.x *= dv; f.y *= dv;
        __hip_bfloat162 r = __float22bfloat162_rn(f);
        h2[(size_t)node * 16 + q] = *(unsigned*)&r;                 // hs = h * dinv
    }
}

// ---------------- B2: direct LDS-atomic accumulation; fused self+bias store ----------------
__global__ __launch_bounds__(512) void passB2_k(const unsigned* __restrict__ bucketed,
                                                const int* __restrict__ bcursor,
                                                const __hip_bfloat16* __restrict__ hs,
                                                const float* __restrict__ dinv,
                                                const float* __restrict__ bias,
                                                float* __restrict__ out, int n) {
    __shared__ unsigned stage[CAP];      // 16 KB
    __shared__ float oacc[BW][LATD];     // 16 KB accumulator tile (this block owns dst rows)
    int tid = threadIdx.x;
    int b = blockIdx.x;
    size_t s = (size_t)b * CAP;
    int tot = bcursor[b]; if (tot > CAP) tot = CAP;
    int dst0 = b << BSH;
    for (int i = tid; i < BW * LATD; i += 512) ((float*)oacc)[i] = 0.f;
    for (int i = tid; i < tot; i += 512) stage[i] = bucketed[s + i];
    __syncthreads();
    int g = tid >> 5, j = tid & 31;
    for (int base = g * 16; base < tot; base += 16 * 16) {
        int mm = tot - base; if (mm > 16) mm = 16;
        if (mm == 16) {
            unsigned pk[16]; float v[16];
#pragma unroll
            for (int t = 0; t < 16; ++t) {
                pk[t] = stage[base + t];                                   // LDS broadcast
                v[t] = __bfloat162float(hs[(size_t)(pk[t] >> BSH) * LATD + j]);
            }
#pragma unroll
            for (int t = 0; t < 16; ++t)
                atomicAdd(&oacc[pk[t] & (BW - 1)][j], v[t]);               // ds_add_f32 (no rtn)
        } else {
#pragma unroll 4
            for (int t = 0; t < mm; ++t) {
                unsigned pk = stage[base + t];
                float v = __bfloat162float(hs[(size_t)(pk >> BSH) * LATD + j]);
                atomicAdd(&oacc[pk & (BW - 1)][j], v);
            }
        }
    }
    __syncthreads();
    // out = (neigh_acc + hs_self) * dinv + bias   (hs already = h * dinv)
    for (int idx = tid; idx < BW * (LATD / 4); idx += 512) {
        int ld = idx >> 3, q = idx & 7;
        int node = dst0 + ld;
        if (node >= n) continue;
        float dv = dinv[node];
        int j0 = q * 4;
        ushort4 u = *(const ushort4*)&hs[(size_t)node * LATD + j0];
        float4 bv = *(const float4*)&bias[j0];
        float4 o;
        o.x = (oacc[ld][j0 + 0] + __bfloat162float(*(const __hip_bfloat16*)&u.x)) * dv + bv.x;
        o.y = (oacc[ld][j0 + 1] + __bfloat162float(*(const __hip_bfloat16*)&u.y)) * dv + bv.y;
        o.z = (oacc[ld][j0 + 2] + __bfloat162float(*(const __hip_bfloat16*)&u.z)) * dv + bv.z;
        o.w = (oacc[ld][j0 + 3] + __bfloat162float(*(const __hip_bfloat16*)&u.w)) * dv + bv.w;
        *(float4*)&out[(size_t)node * LATD + j0] = o;
    }
}

// ---------------- fallback path (atomic scatter; uses UNSCALED h) ----------------
__global__ void count_k(const int* __restrict__ ei, const int* __restrict__ yei,
                        int* __restrict__ cnt, int e1, int e2) {
    int e = blockIdx.x * 256 + threadIdx.x;
    if (e >= e1 + e2) return;
    int src, dst; load_edge(ei, yei, e1, e2, e, src, dst);
    atomicAdd(&cnt[dst], 1);
}

__global__ void dinv_k(const int* __restrict__ cnt, float* __restrict__ dinv, int n) {
    int i = blockIdx.x * 256 + threadIdx.x;
    if (i < n) dinv[i] = rsqrtf((float)cnt[i] + 1.0f);
}

__global__ void selfbias_k(const float* __restrict__ dinv, const __hip_bfloat16* __restrict__ h,
                           const float* __restrict__ b, float* __restrict__ out, int total) {
    int idx = blockIdx.x * 256 + threadIdx.x;
    if (idx >= total) return;
    int i = idx >> 5, j = idx & 31;
    float d = dinv[i];
    out[idx] = __bfloat162float(h[idx]) * d * d + b[j];
}

__global__ void scatter_atomic_k(const int* __restrict__ ei, const int* __restrict__ yei,
                                 const float* __restrict__ dinv, const __hip_bfloat16* __restrict__ h,
                                 float* __restrict__ out, int e1, int e2) {
    int idx = blockIdx.x * 256 + threadIdx.x;
    int e = idx >> 5;
    if (e >= e1 + e2) return;
    int j = idx & 31;
    int src, dst; load_edge(ei, yei, e1, e2, e, src, dst);
    float norm = dinv[src] * dinv[dst];
    atomicAdd(&out[(size_t)dst * LATD + j], __bfloat162float(h[(size_t)src * LATD + j]) * norm);
}

static inline size_t aln(size_t x) { return (x + 255) & ~(size_t)255; }

extern "C" void kernel_launch(void* const* d_in, const int* in_sizes, int n_in,
                              void* d_out, int out_size, void* d_ws, size_t ws_size,
                              hipStream_t stream) {
    const float* x  = (const float*)d_in[0];
    const int* ei   = (const int*)d_in[1];
    const int* yei  = (const int*)d_in[2];
    const float* W  = (const float*)d_in[3];
    const float* b  = (const float*)d_in[4];
    float* out = (float*)d_out;

    int n  = in_sizes[0] / INCH;
    int e1 = in_sizes[1] / 2;
    int e2 = in_sizes[2] / 2;
    int E  = e1 + e2;
    int NB = (n + BW - 1) >> BSH;

    char* p = (char*)d_ws;
    size_t off = 0;
    float* dinv = (float*)(p + off);            off += aln((size_t)n * 4);
    __hip_bfloat16* h = (__hip_bfloat16*)(p + off); off += aln((size_t)n * LATD * 2);
    unsigned* bucketed = (unsigned*)(p + off);  size_t bucketed_off = off; off += aln((size_t)NB * CAP * 4);
    int* bcursor = (int*)(p + off); off += aln(1024 * 4);
    bool fast_ok = (off <= ws_size) && (NB <= 1024);

    gemm_tile_k<<<(n + 63) / 64, 256, 0, stream>>>(x, W, h, n);

    if (fast_ok) {
        int ablocks = (E + ACH - 1) / ACH;
        zero_i32_k<<<4, 256, 0, stream>>>(bcursor, 1024);
        passA_scatter_k<<<ablocks, 512, 0, stream>>>(ei, yei, e1, e2, bcursor, bucketed, NB);
        passB1deg_k<<<NB, 512, 0, stream>>>(bucketed, bcursor, dinv, (unsigned*)h, n);
        passB2_k<<<NB, 512, 0, stream>>>(bucketed, bcursor, h, dinv, b, out, n);
    } else {
        int* cnt = (int*)(p + bucketed_off);
        zero_i32_k<<<(n + 255) / 256, 256, 0, stream>>>(cnt, n);
        count_k<<<(E + 255) / 256, 256, 0, stream>>>(ei, yei, cnt, e1, e2);
        dinv_k<<<(n + 255) / 256, 256, 0, stream>>>(cnt, dinv, n);
        selfbias_k<<<(out_size + 255) / 256, 256, 0, stream>>>(dinv, h, b, out, out_size);
        scatter_atomic_k<<<((size_t)E * LATD + 255) / 256, 256, 0, stream>>>(ei, yei, dinv, h, out, e1, e2);
    }
}

// Round 2
// 578.456 us; speedup vs baseline: 1.0021x; 1.0021x over previous
//
#include <hip/hip_runtime.h>
#include <hip/hip_bf16.h>

// GCNConv encoder — R16:
//   passA:  ACH=2048, single global edge read, LDS multisplit -> buckets (CAP=4096)  [unchanged]
//   B1deg:  histogram degree -> dinv, scale h*=dinv in place
//   B2:     direct accumulation into oacc[128][32] via RAW ds_add_f32 (hw fp32 LDS atomic,
//           no-return; hipcc's atomicAdd(float*) on LDS emits a CAS loop — R15's 433us bug),
//           MLP-16 gather batches; fused (neigh+self)*dinv+bias float4 store.
//   gemm:   64-row tile (33.4 KB LDS)  [unchanged]
//
// ws: dinv[n] f32 | h[n*32] bf16 | bucketed[NB*CAP] u32 | bcursor[1024] ~= 19.7 MB

#define LATD 32
#define INCH 128
#define BSH 7
#define BW 128
#define CAP 4096
#define ACH 2048

__device__ __forceinline__ void lds_fadd(float* p, float v) {
    // generic pointer to __shared__ has the 32-bit LDS byte offset in its low word
    unsigned off = (unsigned)(unsigned long long)p;
    asm volatile("ds_add_f32 %0, %1" :: "v"(off), "v"(v) : "memory");
}

__device__ __forceinline__ void load_edge(const int* __restrict__ ei, const int* __restrict__ yei,
                                          int e1, int e2, int e, int& src, int& dst) {
    if (e < e1) { src = ei[e]; dst = ei[e1 + e]; }
    else        { int t = e - e1; src = yei[t]; dst = yei[e2 + t]; }
}

// ---------------- GEMM v3 (proven R14): 64-row tile, bf16 x-staging, 256 thr ----------------
__global__ __launch_bounds__(256) void gemm_tile_k(const float* __restrict__ x,
                                                   const float* __restrict__ W,
                                                   __hip_bfloat16* __restrict__ h, int n) {
    __shared__ __hip_bfloat16 xs[64][136];
    __shared__ float Wl[INCH][LATD];
    int tid = threadIdx.x;
    {
        const float4* Wv = (const float4*)W;
        float4* Wlv = (float4*)&Wl[0][0];
#pragma unroll 2
        for (int i = 0; i < 4; ++i) Wlv[tid + 256 * i] = Wv[tid + 256 * i];
    }
    int row0 = blockIdx.x * 64;
#pragma unroll 4
    for (int v = tid; v < 64 * 32; v += 256) {
        int r = v >> 5, kc = v & 31;
        int gr = row0 + r;
        float4 val = make_float4(0.f, 0.f, 0.f, 0.f);
        if (gr < n) val = ((const float4*)(x + (size_t)gr * INCH))[kc];
        __hip_bfloat16 t4[4] = { __float2bfloat16(val.x), __float2bfloat16(val.y),
                                 __float2bfloat16(val.z), __float2bfloat16(val.w) };
        *(ushort4*)&xs[r][kc * 4] = *(const ushort4*)t4;
    }
    __syncthreads();
    int c = tid & 7, rr = tid >> 3;
    int j0 = c * 4, r0 = rr * 2;
    float acc[2][4] = {};
#pragma unroll 2
    for (int kk = 0; kk < INCH; kk += 4) {
        float4 w0 = *(const float4*)&Wl[kk + 0][j0];
        float4 w1 = *(const float4*)&Wl[kk + 1][j0];
        float4 w2 = *(const float4*)&Wl[kk + 2][j0];
        float4 w3 = *(const float4*)&Wl[kk + 3][j0];
#pragma unroll
        for (int ri = 0; ri < 2; ++ri) {
            ushort4 u = *(const ushort4*)&xs[r0 + ri][kk];
            float a0 = __bfloat162float(*(const __hip_bfloat16*)&u.x);
            float a1 = __bfloat162float(*(const __hip_bfloat16*)&u.y);
            float a2 = __bfloat162float(*(const __hip_bfloat16*)&u.z);
            float a3 = __bfloat162float(*(const __hip_bfloat16*)&u.w);
            acc[ri][0] += a0 * w0.x + a1 * w1.x + a2 * w2.x + a3 * w3.x;
            acc[ri][1] += a0 * w0.y + a1 * w1.y + a2 * w2.y + a3 * w3.y;
            acc[ri][2] += a0 * w0.z + a1 * w1.z + a2 * w2.z + a3 * w3.z;
            acc[ri][3] += a0 * w0.w + a1 * w1.w + a2 * w2.w + a3 * w3.w;
        }
    }
#pragma unroll
    for (int ri = 0; ri < 2; ++ri) {
        int gr = row0 + r0 + ri;
        if (gr < n) {
            __hip_bfloat16 tmp[4];
#pragma unroll
            for (int cj = 0; cj < 4; ++cj) tmp[cj] = __float2bfloat16(acc[ri][cj]);
            *(ushort4*)(&h[(size_t)gr * LATD + j0]) = *(const ushort4*)tmp;
        }
    }
}

__global__ void zero_i32_k(int* p, int cnt) {
    int i = blockIdx.x * 256 + threadIdx.x;
    if (i < cnt) p[i] = 0;
}

// ---------------- pass A: single-global-read multisplit (ACH=2048) ----------------
__global__ __launch_bounds__(512) void passA_scatter_k(const int* __restrict__ ei, const int* __restrict__ yei,
                                                       int e1, int e2, int* __restrict__ bcursor,
                                                       unsigned* __restrict__ bucketed, int NB) {
    __shared__ int hist[1024];
    __shared__ int scanex[1024];
    __shared__ int segb[1024];
    __shared__ int sd[512];
    __shared__ unsigned raw[ACH];           // pk in arrival order
    __shared__ unsigned short rawb[ACH];    // bucket in arrival order
    __shared__ unsigned stage[ACH];         // pk sorted by bucket
    __shared__ unsigned short bof[ACH];     // bucket sorted
    int tid = threadIdx.x;
    int E = e1 + e2;
    int e0 = blockIdx.x * ACH;
    int m = E - e0; if (m > ACH) m = ACH;
    for (int i = tid; i < 1024; i += 512) hist[i] = 0;
    __syncthreads();
    for (int i = tid; i < m; i += 512) {
        int src, dst; load_edge(ei, yei, e1, e2, e0 + i, src, dst);
        int b = dst >> BSH;
        raw[i]  = ((unsigned)src << BSH) | (unsigned)(dst & (BW - 1));
        rawb[i] = (unsigned short)b;
        atomicAdd(&hist[b], 1);
    }
    __syncthreads();
    int b2 = tid * 2;
    int c0 = hist[b2], c1 = hist[b2 + 1];
    int tot2 = c0 + c1;
    sd[tid] = tot2;
    __syncthreads();
    int val = tot2;
    for (int off = 1; off < 512; off <<= 1) {
        int t = (tid >= off) ? sd[tid - off] : 0;
        __syncthreads();
        val += t;
        sd[tid] = val;
        __syncthreads();
    }
    int eb = val - tot2;
    scanex[b2] = eb; scanex[b2 + 1] = eb + c0;
    __syncthreads();
    for (int b = tid; b < NB; b += 512)
        segb[b] = hist[b] ? atomicAdd(&bcursor[b], hist[b]) : 0;
    __syncthreads();
    for (int b = tid; b < 1024; b += 512) hist[b] = scanex[b];   // repurpose as cursor
    __syncthreads();
    for (int i = tid; i < m; i += 512) {
        unsigned pk = raw[i]; int b = rawb[i];
        int pos = atomicAdd(&hist[b], 1);
        stage[pos] = pk;
        bof[pos] = (unsigned short)b;
    }
    __syncthreads();
    for (int i = tid; i < m; i += 512) {
        int b = bof[i];
        int pos = segb[b] + (i - scanex[b]);
        if (pos < CAP)
            bucketed[(size_t)b * CAP + pos] = stage[i];
    }
}

// ---------------- B1deg: histogram degree; dinv; scale h in place ----------------
__global__ __launch_bounds__(512) void passB1deg_k(const unsigned* __restrict__ bucketed,
                                                   const int* __restrict__ bcursor,
                                                   float* __restrict__ dinv, unsigned* __restrict__ h2,
                                                   int n) {
    __shared__ int cnt[BW];
    __shared__ float sdv[BW];
    int tid = threadIdx.x;
    int b = blockIdx.x;
    size_t s = (size_t)b * CAP;
    int tot = bcursor[b]; if (tot > CAP) tot = CAP;
    int dst0 = b << BSH;
    if (tid < BW) cnt[tid] = 0;
    __syncthreads();
    for (int i = tid; i < tot; i += 512)
        atomicAdd(&cnt[bucketed[s + i] & (BW - 1)], 1);
    __syncthreads();
    if (tid < BW) {
        float dv = rsqrtf((float)cnt[tid] + 1.0f);
        sdv[tid] = dv;
        int node = dst0 + tid;
        if (node < n) dinv[node] = dv;
    }
    __syncthreads();
    for (int idx = tid; idx < BW * 16; idx += 512) {
        int ldn = idx >> 4, q = idx & 15;
        int node = dst0 + ldn;
        if (node >= n) continue;
        float dv = sdv[ldn];
        unsigned u = h2[(size_t)node * 16 + q];
        __hip_bfloat162 v = *(__hip_bfloat162*)&u;
        float2 f = __bfloat1622float2(v);
        f.x *= dv; f.y *= dv;
        __hip_bfloat162 r = __float22bfloat162_rn(f);
        h2[(size_t)node * 16 + q] = *(unsigned*)&r;                 // hs = h * dinv
    }
}

// ---------------- B2: direct ds_add_f32 accumulation; fused self+bias store ----------------
__global__ __launch_bounds__(512) void passB2_k(const unsigned* __restrict__ bucketed,
                                                const int* __restrict__ bcursor,
                                                const __hip_bfloat16* __restrict__ hs,
                                                const float* __restrict__ dinv,
                                                const float* __restrict__ bias,
                                                float* __restrict__ out, int n) {
    __shared__ unsigned stage[CAP];      // 16 KB
    __shared__ float oacc[BW][LATD];     // 16 KB accumulator tile (this block owns dst rows)
    int tid = threadIdx.x;
    int b = blockIdx.x;
    size_t s = (size_t)b * CAP;
    int tot = bcursor[b]; if (tot > CAP) tot = CAP;
    int dst0 = b << BSH;
    for (int i = tid; i < BW * LATD; i += 512) ((float*)oacc)[i] = 0.f;
    for (int i = tid; i < tot; i += 512) stage[i] = bucketed[s + i];
    __syncthreads();
    int g = tid >> 5, j = tid & 31;
    for (int base = g * 16; base < tot; base += 16 * 16) {
        int mm = tot - base; if (mm > 16) mm = 16;
        if (mm == 16) {
            unsigned pk[16]; float v[16];
#pragma unroll
            for (int t = 0; t < 16; ++t) {
                pk[t] = stage[base + t];                                   // LDS broadcast
                v[t] = __bfloat162float(hs[(size_t)(pk[t] >> BSH) * LATD + j]);
            }
#pragma unroll
            for (int t = 0; t < 16; ++t)
                lds_fadd(&oacc[pk[t] & (BW - 1)][j], v[t]);                // hw ds_add_f32
        } else {
#pragma unroll 4
            for (int t = 0; t < mm; ++t) {
                unsigned pk = stage[base + t];
                float v = __bfloat162float(hs[(size_t)(pk >> BSH) * LATD + j]);
                lds_fadd(&oacc[pk & (BW - 1)][j], v);
            }
        }
    }
    __syncthreads();
    // out = (neigh_acc + hs_self) * dinv + bias   (hs already = h * dinv)
    for (int idx = tid; idx < BW * (LATD / 4); idx += 512) {
        int ld = idx >> 3, q = idx & 7;
        int node = dst0 + ld;
        if (node >= n) continue;
        float dv = dinv[node];
        int j0 = q * 4;
        ushort4 u = *(const ushort4*)&hs[(size_t)node * LATD + j0];
        float4 bv = *(const float4*)&bias[j0];
        float4 o;
        o.x = (oacc[ld][j0 + 0] + __bfloat162float(*(const __hip_bfloat16*)&u.x)) * dv + bv.x;
        o.y = (oacc[ld][j0 + 1] + __bfloat162float(*(const __hip_bfloat16*)&u.y)) * dv + bv.y;
        o.z = (oacc[ld][j0 + 2] + __bfloat162float(*(const __hip_bfloat16*)&u.z)) * dv + bv.z;
        o.w = (oacc[ld][j0 + 3] + __bfloat162float(*(const __hip_bfloat16*)&u.w)) * dv + bv.w;
        *(float4*)&out[(size_t)node * LATD + j0] = o;
    }
}

// ---------------- fallback path (atomic scatter; uses UNSCALED h) ----------------
__global__ void count_k(const int* __restrict__ ei, const int* __restrict__ yei,
                        int* __restrict__ cnt, int e1, int e2) {
    int e = blockIdx.x * 256 + threadIdx.x;
    if (e >= e1 + e2) return;
    int src, dst; load_edge(ei, yei, e1, e2, e, src, dst);
    atomicAdd(&cnt[dst], 1);
}

__global__ void dinv_k(const int* __restrict__ cnt, float* __restrict__ dinv, int n) {
    int i = blockIdx.x * 256 + threadIdx.x;
    if (i < n) dinv[i] = rsqrtf((float)cnt[i] + 1.0f);
}

__global__ void selfbias_k(const float* __restrict__ dinv, const __hip_bfloat16* __restrict__ h,
                           const float* __restrict__ b, float* __restrict__ out, int total) {
    int idx = blockIdx.x * 256 + threadIdx.x;
    if (idx >= total) return;
    int i = idx >> 5, j = idx & 31;
    float d = dinv[i];
    out[idx] = __bfloat162float(h[idx]) * d * d + b[j];
}

__global__ void scatter_atomic_k(const int* __restrict__ ei, const int* __restrict__ yei,
                                 const float* __restrict__ dinv, const __hip_bfloat16* __restrict__ h,
                                 float* __restrict__ out, int e1, int e2) {
    int idx = blockIdx.x * 256 + threadIdx.x;
    int e = idx >> 5;
    if (e >= e1 + e2) return;
    int j = idx & 31;
    int src, dst; load_edge(ei, yei, e1, e2, e, src, dst);
    float norm = dinv[src] * dinv[dst];
    atomicAdd(&out[(size_t)dst * LATD + j], __bfloat162float(h[(size_t)src * LATD + j]) * norm);
}

static inline size_t aln(size_t x) { return (x + 255) & ~(size_t)255; }

extern "C" void kernel_launch(void* const* d_in, const int* in_sizes, int n_in,
                              void* d_out, int out_size, void* d_ws, size_t ws_size,
                              hipStream_t stream) {
    const float* x  = (const float*)d_in[0];
    const int* ei   = (const int*)d_in[1];
    const int* yei  = (const int*)d_in[2];
    const float* W  = (const float*)d_in[3];
    const float* b  = (const float*)d_in[4];
    float* out = (float*)d_out;

    int n  = in_sizes[0] / INCH;
    int e1 = in_sizes[1] / 2;
    int e2 = in_sizes[2] / 2;
    int E  = e1 + e2;
    int NB = (n + BW - 1) >> BSH;

    char* p = (char*)d_ws;
    size_t off = 0;
    float* dinv = (float*)(p + off);            off += aln((size_t)n * 4);
    __hip_bfloat16* h = (__hip_bfloat16*)(p + off); off += aln((size_t)n * LATD * 2);
    unsigned* bucketed = (unsigned*)(p + off);  size_t bucketed_off = off; off += aln((size_t)NB * CAP * 4);
    int* bcursor = (int*)(p + off); off += aln(1024 * 4);
    bool fast_ok = (off <= ws_size) && (NB <= 1024);

    gemm_tile_k<<<(n + 63) / 64, 256, 0, stream>>>(x, W, h, n);

    if (fast_ok) {
        int ablocks = (E + ACH - 1) / ACH;
        zero_i32_k<<<4, 256, 0, stream>>>(bcursor, 1024);
        passA_scatter_k<<<ablocks, 512, 0, stream>>>(ei, yei, e1, e2, bcursor, bucketed, NB);
        passB1deg_k<<<NB, 512, 0, stream>>>(bucketed, bcursor, dinv, (unsigned*)h, n);
        passB2_k<<<NB, 512, 0, stream>>>(bucketed, bcursor, h, dinv, b, out, n);
    } else {
        int* cnt = (int*)(p + bucketed_off);
        zero_i32_k<<<(n + 255) / 256, 256, 0, stream>>>(cnt, n);
        count_k<<<(E + 255) / 256, 256, 0, stream>>>(ei, yei, cnt, e1, e2);
        dinv_k<<<(n + 255) / 256, 256, 0, stream>>>(cnt, dinv, n);
        selfbias_k<<<(out_size + 255) / 256, 256, 0, stream>>>(dinv, h, b, out, out_size);
        scatter_atomic_k<<<((size_t)E * LATD + 255) / 256, 256, 0, stream>>>(ei, yei, dinv, h, out, e1, e2);
    }
}

// Round 3
// 196.412 us; speedup vs baseline: 2.9513x; 2.9451x over previous
//
#include <hip/hip_runtime.h>
#include <hip/hip_bf16.h>

// GCNConv encoder — R17:
//   passA:  ACH=2048, single global edge read, LDS multisplit -> buckets (CAP=4096)  [unchanged]
//   B1deg:  histogram degree -> dinv, scale h*=dinv in place (does NOT write out)
//   B2:     R14-proven counting sort + register-accumulating segmented sweep (MLP-16
//           gathers with NO memory ops in the inner loop -> compiler pipelines them),
//           segment flush via ds_add_f32 into block-owned oacc[128][32] (~144 wave-ops),
//           fused (neigh+self)*dinv+bias float4 epilogue store.
//           LESSON (R15/R16, both 433us): per-EDGE LDS atomics (CAS or raw ds_add) in the
//           gather loop defeat load batching -> serial full-latency chain per edge.
//   gemm:   64-row tile (33.4 KB LDS)  [unchanged]
//
// ws: dinv[n] f32 | h[n*32] bf16 | bucketed[NB*CAP] u32 | bcursor[1024] ~= 19.7 MB

#define LATD 32
#define INCH 128
#define BSH 7
#define BW 128
#define CAP 4096
#define ACH 2048

__device__ __forceinline__ void lds_fadd(float* p, float v) {
    // generic pointer to __shared__ carries the 32-bit LDS byte offset in its low word
    unsigned off = (unsigned)(unsigned long long)p;
    asm volatile("ds_add_f32 %0, %1" :: "v"(off), "v"(v) : "memory");
}

__device__ __forceinline__ void load_edge(const int* __restrict__ ei, const int* __restrict__ yei,
                                          int e1, int e2, int e, int& src, int& dst) {
    if (e < e1) { src = ei[e]; dst = ei[e1 + e]; }
    else        { int t = e - e1; src = yei[t]; dst = yei[e2 + t]; }
}

// ---------------- GEMM v3 (proven R14): 64-row tile, bf16 x-staging, 256 thr ----------------
__global__ __launch_bounds__(256) void gemm_tile_k(const float* __restrict__ x,
                                                   const float* __restrict__ W,
                                                   __hip_bfloat16* __restrict__ h, int n) {
    __shared__ __hip_bfloat16 xs[64][136];
    __shared__ float Wl[INCH][LATD];
    int tid = threadIdx.x;
    {
        const float4* Wv = (const float4*)W;
        float4* Wlv = (float4*)&Wl[0][0];
#pragma unroll 2
        for (int i = 0; i < 4; ++i) Wlv[tid + 256 * i] = Wv[tid + 256 * i];
    }
    int row0 = blockIdx.x * 64;
#pragma unroll 4
    for (int v = tid; v < 64 * 32; v += 256) {
        int r = v >> 5, kc = v & 31;
        int gr = row0 + r;
        float4 val = make_float4(0.f, 0.f, 0.f, 0.f);
        if (gr < n) val = ((const float4*)(x + (size_t)gr * INCH))[kc];
        __hip_bfloat16 t4[4] = { __float2bfloat16(val.x), __float2bfloat16(val.y),
                                 __float2bfloat16(val.z), __float2bfloat16(val.w) };
        *(ushort4*)&xs[r][kc * 4] = *(const ushort4*)t4;
    }
    __syncthreads();
    int c = tid & 7, rr = tid >> 3;
    int j0 = c * 4, r0 = rr * 2;
    float acc[2][4] = {};
#pragma unroll 2
    for (int kk = 0; kk < INCH; kk += 4) {
        float4 w0 = *(const float4*)&Wl[kk + 0][j0];
        float4 w1 = *(const float4*)&Wl[kk + 1][j0];
        float4 w2 = *(const float4*)&Wl[kk + 2][j0];
        float4 w3 = *(const float4*)&Wl[kk + 3][j0];
#pragma unroll
        for (int ri = 0; ri < 2; ++ri) {
            ushort4 u = *(const ushort4*)&xs[r0 + ri][kk];
            float a0 = __bfloat162float(*(const __hip_bfloat16*)&u.x);
            float a1 = __bfloat162float(*(const __hip_bfloat16*)&u.y);
            float a2 = __bfloat162float(*(const __hip_bfloat16*)&u.z);
            float a3 = __bfloat162float(*(const __hip_bfloat16*)&u.w);
            acc[ri][0] += a0 * w0.x + a1 * w1.x + a2 * w2.x + a3 * w3.x;
            acc[ri][1] += a0 * w0.y + a1 * w1.y + a2 * w2.y + a3 * w3.y;
            acc[ri][2] += a0 * w0.z + a1 * w1.z + a2 * w2.z + a3 * w3.z;
            acc[ri][3] += a0 * w0.w + a1 * w1.w + a2 * w2.w + a3 * w3.w;
        }
    }
#pragma unroll
    for (int ri = 0; ri < 2; ++ri) {
        int gr = row0 + r0 + ri;
        if (gr < n) {
            __hip_bfloat16 tmp[4];
#pragma unroll
            for (int cj = 0; cj < 4; ++cj) tmp[cj] = __float2bfloat16(acc[ri][cj]);
            *(ushort4*)(&h[(size_t)gr * LATD + j0]) = *(const ushort4*)tmp;
        }
    }
}

__global__ void zero_i32_k(int* p, int cnt) {
    int i = blockIdx.x * 256 + threadIdx.x;
    if (i < cnt) p[i] = 0;
}

// ---------------- pass A: single-global-read multisplit (ACH=2048) ----------------
__global__ __launch_bounds__(512) void passA_scatter_k(const int* __restrict__ ei, const int* __restrict__ yei,
                                                       int e1, int e2, int* __restrict__ bcursor,
                                                       unsigned* __restrict__ bucketed, int NB) {
    __shared__ int hist[1024];
    __shared__ int scanex[1024];
    __shared__ int segb[1024];
    __shared__ int sd[512];
    __shared__ unsigned raw[ACH];           // pk in arrival order
    __shared__ unsigned short rawb[ACH];    // bucket in arrival order
    __shared__ unsigned stage[ACH];         // pk sorted by bucket
    __shared__ unsigned short bof[ACH];     // bucket sorted
    int tid = threadIdx.x;
    int E = e1 + e2;
    int e0 = blockIdx.x * ACH;
    int m = E - e0; if (m > ACH) m = ACH;
    for (int i = tid; i < 1024; i += 512) hist[i] = 0;
    __syncthreads();
    for (int i = tid; i < m; i += 512) {
        int src, dst; load_edge(ei, yei, e1, e2, e0 + i, src, dst);
        int b = dst >> BSH;
        raw[i]  = ((unsigned)src << BSH) | (unsigned)(dst & (BW - 1));
        rawb[i] = (unsigned short)b;
        atomicAdd(&hist[b], 1);
    }
    __syncthreads();
    int b2 = tid * 2;
    int c0 = hist[b2], c1 = hist[b2 + 1];
    int tot2 = c0 + c1;
    sd[tid] = tot2;
    __syncthreads();
    int val = tot2;
    for (int off = 1; off < 512; off <<= 1) {
        int t = (tid >= off) ? sd[tid - off] : 0;
        __syncthreads();
        val += t;
        sd[tid] = val;
        __syncthreads();
    }
    int eb = val - tot2;
    scanex[b2] = eb; scanex[b2 + 1] = eb + c0;
    __syncthreads();
    for (int b = tid; b < NB; b += 512)
        segb[b] = hist[b] ? atomicAdd(&bcursor[b], hist[b]) : 0;
    __syncthreads();
    for (int b = tid; b < 1024; b += 512) hist[b] = scanex[b];   // repurpose as cursor
    __syncthreads();
    for (int i = tid; i < m; i += 512) {
        unsigned pk = raw[i]; int b = rawb[i];
        int pos = atomicAdd(&hist[b], 1);
        stage[pos] = pk;
        bof[pos] = (unsigned short)b;
    }
    __syncthreads();
    for (int i = tid; i < m; i += 512) {
        int b = bof[i];
        int pos = segb[b] + (i - scanex[b]);
        if (pos < CAP)
            bucketed[(size_t)b * CAP + pos] = stage[i];
    }
}

// ---------------- B1deg: histogram degree; dinv; scale h in place ----------------
__global__ __launch_bounds__(512) void passB1deg_k(const unsigned* __restrict__ bucketed,
                                                   const int* __restrict__ bcursor,
                                                   float* __restrict__ dinv, unsigned* __restrict__ h2,
                                                   int n) {
    __shared__ int cnt[BW];
    __shared__ float sdv[BW];
    int tid = threadIdx.x;
    int b = blockIdx.x;
    size_t s = (size_t)b * CAP;
    int tot = bcursor[b]; if (tot > CAP) tot = CAP;
    int dst0 = b << BSH;
    if (tid < BW) cnt[tid] = 0;
    __syncthreads();
    for (int i = tid; i < tot; i += 512)
        atomicAdd(&cnt[bucketed[s + i] & (BW - 1)], 1);
    __syncthreads();
    if (tid < BW) {
        float dv = rsqrtf((float)cnt[tid] + 1.0f);
        sdv[tid] = dv;
        int node = dst0 + tid;
        if (node < n) dinv[node] = dv;
    }
    __syncthreads();
    for (int idx = tid; idx < BW * 16; idx += 512) {
        int ldn = idx >> 4, q = idx & 15;
        int node = dst0 + ldn;
        if (node >= n) continue;
        float dv = sdv[ldn];
        unsigned u = h2[(size_t)node * 16 + q];
        __hip_bfloat162 v = *(__hip_bfloat162*)&u;
        float2 f = __bfloat1622float2(v);
        f.x *= dv; f.y *= dv;
        __hip_bfloat162 r = __float22bfloat162_rn(f);
        h2[(size_t)node * 16 + q] = *(unsigned*)&r;                 // hs = h * dinv
    }
}

// ---------------- B2: counting sort + register sweep; ds_add flush; fused store ----------------
__global__ __launch_bounds__(512) void passB2_k(const unsigned* __restrict__ bucketed,
                                                const int* __restrict__ bcursor,
                                                const __hip_bfloat16* __restrict__ hs,
                                                const float* __restrict__ dinv,
                                                const float* __restrict__ bias,
                                                float* __restrict__ out, int n) {
    __shared__ unsigned sorted[CAP];     // 16 KB
    __shared__ float oacc[BW][LATD];     // 16 KB accumulator tile (this block owns dst rows)
    __shared__ int cnt[BW], row[BW], cur[BW];
    int tid = threadIdx.x;
    int b = blockIdx.x;
    size_t s = (size_t)b * CAP;
    int tot = bcursor[b]; if (tot > CAP) tot = CAP;
    int dst0 = b << BSH;
    for (int i = tid; i < BW * LATD; i += 512) ((float*)oacc)[i] = 0.f;
    if (tid < BW) cnt[tid] = 0;
    __syncthreads();
    // pass 1: degree histogram (sequential coalesced global read, L2-warm)
    for (int i = tid; i < tot; i += 512)
        atomicAdd(&cnt[bucketed[s + i] & (BW - 1)], 1);
    __syncthreads();
    if (tid < BW) row[tid] = cnt[tid];
    __syncthreads();
    for (int off = 1; off < BW; off <<= 1) {
        int t = 0;
        if (tid < BW && tid >= off) t = row[tid - off];
        __syncthreads();
        if (tid < BW) row[tid] += t;
        __syncthreads();
    }
    if (tid < BW) cur[tid] = row[tid] - cnt[tid];
    __syncthreads();
    // pass 2: counting-sort scatter into LDS (second sequential global read)
    for (int i = tid; i < tot; i += 512) {
        unsigned e = bucketed[s + i];
        int p = atomicAdd(&cur[e & (BW - 1)], 1);
        sorted[p] = e;
    }
    __syncthreads();
    // segmented sweep: register accumulation, MLP-16 gather batches (NO memory ops
    // in the gather loop), rare ds_add_f32 flush per node-segment
    int g = tid >> 5, j = tid & 31;
    int span = (((tot + 15) >> 4) + 31) & ~31;
    int gs = g * span;
    int ge = gs + span; if (ge > tot) ge = tot;
    if (gs < tot) {
        float acc = 0.0f;
        int cur_ld = -1;
        for (int base = gs; base < ge; base += 32) {
            int mm = ge - base; if (mm > 32) mm = 32;
            if (mm == 32) {
#pragma unroll
                for (int ph = 0; ph < 2; ++ph) {
                    unsigned pk16[16]; float v16[16];
#pragma unroll
                    for (int t = 0; t < 16; ++t) {
                        pk16[t] = sorted[base + ph * 16 + t];              // LDS broadcast
                        v16[t] = __bfloat162float(hs[(size_t)(pk16[t] >> BSH) * LATD + j]);
                    }
#pragma unroll
                    for (int t = 0; t < 16; ++t) {
                        int ld = (int)(pk16[t] & (BW - 1));
                        if (ld != cur_ld) {
                            if (cur_ld >= 0) lds_fadd(&oacc[cur_ld][j], acc);
                            cur_ld = ld; acc = 0.0f;
                        }
                        acc += v16[t];
                    }
                }
            } else {
#pragma unroll 4
                for (int t = 0; t < mm; ++t) {
                    unsigned pk = sorted[base + t];
                    float v = __bfloat162float(hs[(size_t)(pk >> BSH) * LATD + j]);
                    int ld = (int)(pk & (BW - 1));
                    if (ld != cur_ld) {
                        if (cur_ld >= 0) lds_fadd(&oacc[cur_ld][j], acc);
                        cur_ld = ld; acc = 0.0f;
                    }
                    acc += v;
                }
            }
        }
        if (cur_ld >= 0) lds_fadd(&oacc[cur_ld][j], acc);
    }
    __syncthreads();   // waits lgkmcnt(0) -> all ds_add flushes visible
    // out = (neigh_acc + hs_self) * dinv + bias   (hs already = h * dinv)
    for (int idx = tid; idx < BW * (LATD / 4); idx += 512) {
        int ld = idx >> 3, q = idx & 7;
        int node = dst0 + ld;
        if (node >= n) continue;
        float dv = dinv[node];
        int j0 = q * 4;
        ushort4 u = *(const ushort4*)&hs[(size_t)node * LATD + j0];
        float4 bv = *(const float4*)&bias[j0];
        float4 o;
        o.x = (oacc[ld][j0 + 0] + __bfloat162float(*(const __hip_bfloat16*)&u.x)) * dv + bv.x;
        o.y = (oacc[ld][j0 + 1] + __bfloat162float(*(const __hip_bfloat16*)&u.y)) * dv + bv.y;
        o.z = (oacc[ld][j0 + 2] + __bfloat162float(*(const __hip_bfloat16*)&u.z)) * dv + bv.z;
        o.w = (oacc[ld][j0 + 3] + __bfloat162float(*(const __hip_bfloat16*)&u.w)) * dv + bv.w;
        *(float4*)&out[(size_t)node * LATD + j0] = o;
    }
}

// ---------------- fallback path (atomic scatter; uses UNSCALED h) ----------------
__global__ void count_k(const int* __restrict__ ei, const int* __restrict__ yei,
                        int* __restrict__ cnt, int e1, int e2) {
    int e = blockIdx.x * 256 + threadIdx.x;
    if (e >= e1 + e2) return;
    int src, dst; load_edge(ei, yei, e1, e2, e, src, dst);
    atomicAdd(&cnt[dst], 1);
}

__global__ void dinv_k(const int* __restrict__ cnt, float* __restrict__ dinv, int n) {
    int i = blockIdx.x * 256 + threadIdx.x;
    if (i < n) dinv[i] = rsqrtf((float)cnt[i] + 1.0f);
}

__global__ void selfbias_k(const float* __restrict__ dinv, const __hip_bfloat16* __restrict__ h,
                           const float* __restrict__ b, float* __restrict__ out, int total) {
    int idx = blockIdx.x * 256 + threadIdx.x;
    if (idx >= total) return;
    int i = idx >> 5, j = idx & 31;
    float d = dinv[i];
    out[idx] = __bfloat162float(h[idx]) * d * d + b[j];
}

__global__ void scatter_atomic_k(const int* __restrict__ ei, const int* __restrict__ yei,
                                 const float* __restrict__ dinv, const __hip_bfloat16* __restrict__ h,
                                 float* __restrict__ out, int e1, int e2) {
    int idx = blockIdx.x * 256 + threadIdx.x;
    int e = idx >> 5;
    if (e >= e1 + e2) return;
    int j = idx & 31;
    int src, dst; load_edge(ei, yei, e1, e2, e, src, dst);
    float norm = dinv[src] * dinv[dst];
    atomicAdd(&out[(size_t)dst * LATD + j], __bfloat162float(h[(size_t)src * LATD + j]) * norm);
}

static inline size_t aln(size_t x) { return (x + 255) & ~(size_t)255; }

extern "C" void kernel_launch(void* const* d_in, const int* in_sizes, int n_in,
                              void* d_out, int out_size, void* d_ws, size_t ws_size,
                              hipStream_t stream) {
    const float* x  = (const float*)d_in[0];
    const int* ei   = (const int*)d_in[1];
    const int* yei  = (const int*)d_in[2];
    const float* W  = (const float*)d_in[3];
    const float* b  = (const float*)d_in[4];
    float* out = (float*)d_out;

    int n  = in_sizes[0] / INCH;
    int e1 = in_sizes[1] / 2;
    int e2 = in_sizes[2] / 2;
    int E  = e1 + e2;
    int NB = (n + BW - 1) >> BSH;

    char* p = (char*)d_ws;
    size_t off = 0;
    float* dinv = (float*)(p + off);            off += aln((size_t)n * 4);
    __hip_bfloat16* h = (__hip_bfloat16*)(p + off); off += aln((size_t)n * LATD * 2);
    unsigned* bucketed = (unsigned*)(p + off);  size_t bucketed_off = off; off += aln((size_t)NB * CAP * 4);
    int* bcursor = (int*)(p + off); off += aln(1024 * 4);
    bool fast_ok = (off <= ws_size) && (NB <= 1024);

    gemm_tile_k<<<(n + 63) / 64, 256, 0, stream>>>(x, W, h, n);

    if (fast_ok) {
        int ablocks = (E + ACH - 1) / ACH;
        zero_i32_k<<<4, 256, 0, stream>>>(bcursor, 1024);
        passA_scatter_k<<<ablocks, 512, 0, stream>>>(ei, yei, e1, e2, bcursor, bucketed, NB);
        passB1deg_k<<<NB, 512, 0, stream>>>(bucketed, bcursor, dinv, (unsigned*)h, n);
        passB2_k<<<NB, 512, 0, stream>>>(bucketed, bcursor, h, dinv, b, out, n);
    } else {
        int* cnt = (int*)(p + bucketed_off);
        zero_i32_k<<<(n + 255) / 256, 256, 0, stream>>>(cnt, n);
        count_k<<<(E + 255) / 256, 256, 0, stream>>>(ei, yei, cnt, e1, e2);
        dinv_k<<<(n + 255) / 256, 256, 0, stream>>>(cnt, dinv, n);
        selfbias_k<<<(out_size + 255) / 256, 256, 0, stream>>>(dinv, h, b, out, out_size);
        scatter_atomic_k<<<((size_t)E * LATD + 255) / 256, 256, 0, stream>>>(ei, yei, dinv, h, out, e1, e2);
    }
}